// Round 10
// baseline (113.095 us; speedup 1.0000x reference)
//
#include <hip/hip_runtime.h>
#include <stdint.h>

// SimCLR clear loss, MI355X — round 14: double-buffered gemm K-loop.
//  - Round-9 confirmed launch-chain theory (134.9 -> 110.9). Remaining gemm is
//    latency-bound: 1 tile/block, 8 serial K-steps with vmcnt(0)+2 barriers.
//  - T3 minimum-2-phase: STAGE(buf^1, k+1) issued BEFORE MFMA on buf; one
//    __syncthreads per K-step (drains prefetch after compute). Barriers/tile
//    16 -> 9; stage latency hides under MFMA. LDS 32 -> 64 KB (>=2 blocks/CU ok).
//  - scatter_plan / finalize unchanged from round 9.

#define NROWS 8192
#define DIM   512
#define NCLS  7
#define GEMM_GRID 512

typedef _Float16 f16x8 __attribute__((ext_vector_type(8)));
typedef _Float16 f16x4 __attribute__((ext_vector_type(4)));
typedef float    f32x4 __attribute__((ext_vector_type(4)));

__device__ __forceinline__ void load16_g2l(void* lds, const void* g) {
    auto* l3 = reinterpret_cast<__attribute__((address_space(3))) uint32_t*>(
        reinterpret_cast<uintptr_t>(lds));
    auto* g1 = reinterpret_cast<const __attribute__((address_space(1))) uint32_t*>(
        reinterpret_cast<uintptr_t>(g));
    __builtin_amdgcn_global_load_lds(g1, l3, 16, 0, 0);
}

// ---------------- 1. fused plan + scatter + cast + pos dot ----------------
// Block b (of 512): first-view rows 8b..8b+7 (waves 0,1: 4 each),
// second-view rows +4096 (waves 2,3). All rows of a wave share one segment.
// Per-block redundant plan: 8192 labels -> cnt[128][7] in LDS -> packed
// (prefix|full<<16) shuffle reduction gives this wave's wavebase[7].
__global__ __launch_bounds__(256) void scatter_plan_kernel(const float* __restrict__ x,
                                                           const int* __restrict__ labels,
                                                           _Float16* __restrict__ y,
                                                           float* __restrict__ denomS,
                                                           float* __restrict__ posPart) {
    __shared__ int    halfc[256][8];     // per-half-segment class counts
    __shared__ int    cnt[128][8];       // per-segment class counts
    __shared__ float4 xch[8][128];       // second-view rows for pos dot
    __shared__ float  red[2];
    const int tid  = threadIdx.x;
    const int lane = tid & 63;
    const int wv   = tid >> 6;
    const int b    = blockIdx.x;

    {   // count 32 labels (= half of segment tid>>1)
        const int4* l4 = (const int4*)labels + tid * 8;
        int c0 = 0, c1 = 0, c2 = 0, c3 = 0, c4 = 0, c5 = 0, c6 = 0;
        #pragma unroll
        for (int j = 0; j < 8; ++j) {
            int4 v = l4[j];
            c0 += (v.x == 0) + (v.y == 0) + (v.z == 0) + (v.w == 0);
            c1 += (v.x == 1) + (v.y == 1) + (v.z == 1) + (v.w == 1);
            c2 += (v.x == 2) + (v.y == 2) + (v.z == 2) + (v.w == 2);
            c3 += (v.x == 3) + (v.y == 3) + (v.z == 3) + (v.w == 3);
            c4 += (v.x == 4) + (v.y == 4) + (v.z == 4) + (v.w == 4);
            c5 += (v.x == 5) + (v.y == 5) + (v.z == 5) + (v.w == 5);
            c6 += (v.x == 6) + (v.y == 6) + (v.z == 6) + (v.w == 6);
        }
        halfc[tid][0] = c0; halfc[tid][1] = c1; halfc[tid][2] = c2;
        halfc[tid][3] = c3; halfc[tid][4] = c4; halfc[tid][5] = c5;
        halfc[tid][6] = c6;
    }
    __syncthreads();
    if (tid < 128) {
        #pragma unroll
        for (int c = 0; c < NCLS; ++c)
            cnt[tid][c] = halfc[2 * tid][c] + halfc[2 * tid + 1][c];
    }
    __syncthreads();

    // wave's segment: waves 0,1 -> b>>3 ; waves 2,3 -> b>>3 + 64
    const int s = (b >> 3) + (wv >> 1) * 64;

    // wavebase[c] = class_offset(c) + sum_{s'<s} cnt[s'][c], via packed reduce
    int wb[NCLS];
    {
        int o = 0;
        #pragma unroll
        for (int c = 0; c < NCLS; ++c) {
            int a0 = cnt[lane][c], a1 = cnt[lane + 64][c];
            int p = (lane < s ? a0 : 0) + (lane + 64 < s ? a1 : 0);
            int packed = p | ((a0 + a1) << 16);
            #pragma unroll
            for (int dd = 1; dd < 64; dd <<= 1) packed += __shfl_xor(packed, dd, 64);
            wb[c] = o + (packed & 0xffff);
            o += (packed >> 16);
        }
    }

    // ballot rank within segment
    const int lab = labels[s * 64 + lane];
    unsigned long long m0 = __ballot(lab == 0), m1 = __ballot(lab == 1),
                       m2 = __ballot(lab == 2), m3 = __ballot(lab == 3),
                       m4 = __ballot(lab == 4), m5 = __ballot(lab == 5),
                       m6 = __ballot(lab == 6);
    unsigned long long mymask =
        lab == 0 ? m0 : lab == 1 ? m1 : lab == 2 ? m2 : lab == 3 ? m3 :
        lab == 4 ? m4 : lab == 5 ? m5 : m6;
    int wbsel = lab == 0 ? wb[0] : lab == 1 ? wb[1] : lab == 2 ? wb[2] :
                lab == 3 ? wb[3] : lab == 4 ? wb[4] : lab == 5 ? wb[5] : wb[6];
    const unsigned long long lt = (1ull << lane) - 1ull;
    const int dest_lane = wbsel + __builtin_popcountll(mymask & lt);

    // load 4 rows (lane covers contiguous 8 floats: float4 pair 2*lane, 2*lane+1)
    const int r0 = b * 8 + (wv & 1) * 4 + (wv >> 1) * 4096;
    float4 va[8];
    #pragma unroll
    for (int j = 0; j < 4; ++j) {
        const float4* src = (const float4*)(x + (size_t)(r0 + j) * DIM);
        va[2 * j]     = src[2 * lane];
        va[2 * j + 1] = src[2 * lane + 1];
    }
    if (wv >= 2) {      // publish second view for the pos dot
        #pragma unroll
        for (int j = 0; j < 4; ++j) {
            xch[(wv - 2) * 4 + j][2 * lane]     = va[2 * j];
            xch[(wv - 2) * 4 + j][2 * lane + 1] = va[2 * j + 1];
        }
    }

    // cast + scatter store: one 16B f16x8 per row per lane
    #pragma unroll
    for (int j = 0; j < 4; ++j) {
        int dest = __shfl(dest_lane, (r0 + j) & 63, 64);
        f16x8 h;
        h[0] = (_Float16)va[2 * j].x;     h[1] = (_Float16)va[2 * j].y;
        h[2] = (_Float16)va[2 * j].z;     h[3] = (_Float16)va[2 * j].w;
        h[4] = (_Float16)va[2 * j + 1].x; h[5] = (_Float16)va[2 * j + 1].y;
        h[6] = (_Float16)va[2 * j + 1].z; h[7] = (_Float16)va[2 * j + 1].w;
        *(f16x8*)(y + (size_t)dest * DIM + lane * 8) = h;
    }

    __syncthreads();
    if (wv < 2) {       // first view: dot against paired second-view rows
        float acc = 0.f;
        #pragma unroll
        for (int j = 0; j < 4; ++j) {
            float4 b0 = xch[wv * 4 + j][2 * lane];
            float4 b1 = xch[wv * 4 + j][2 * lane + 1];
            acc += va[2 * j].x * b0.x + va[2 * j].y * b0.y
                 + va[2 * j].z * b0.z + va[2 * j].w * b0.w
                 + va[2 * j + 1].x * b1.x + va[2 * j + 1].y * b1.y
                 + va[2 * j + 1].z * b1.z + va[2 * j + 1].w * b1.w;
        }
        #pragma unroll
        for (int dd = 1; dd < 64; dd <<= 1) acc += __shfl_xor(acc, dd, 64);
        if (lane == 0) red[wv] = acc;
    }
    __syncthreads();
    if (tid == 0) posPart[b] = red[0] + red[1];
    if (tid < 4) ((float4*)denomS)[b * 4 + tid] = make_float4(0.f, 0.f, 0.f, 0.f);
}

// ---------------- 2. GEMM over upper-triangle 128x128 class tiles ----------------
// Tile list derived on the fly from a per-block 7-bin label histogram.
// 8 waves, each a 64x32 quadrant (acc 4x2 of f32x4); LDS fragment-ordered
// [2][8][64][8] per panel, DOUBLE-BUFFERED: prefetch K-step k+1 issued before
// MFMA on k; single barrier per K-step. Off-diag tiles emit row+col sums
// (S^T reuse); diag masks i!=j.
__global__ __launch_bounds__(512) void gemm_denom_kernel(const _Float16* __restrict__ X,
                                                         const int* __restrict__ labels,
                                                         float* __restrict__ denom) {
    __shared__ __align__(16) _Float16 Atile[2][8192];  // 2 x 16 KiB
    __shared__ __align__(16) _Float16 Btile[2][8192];
    __shared__ int whist[8][8];
    __shared__ int s_hist[8], s_off[8], s_tb[8];

    const int tid  = threadIdx.x;
    const int lane = tid & 63;
    const int wv   = tid >> 6;       // 0..7
    const int lc   = lane & 15;
    const int lq   = lane >> 4;
    const int l8   = lq * 8;
    const int wr   = wv >> 2;        // 0..1 : 64-row half
    const int wc   = wv & 3;         // 0..3 : 32-col quarter

    {   // class histogram: 512 threads x 16 labels, wave shuffle reduce
        const int4* l4 = (const int4*)labels + tid * 4;
        int cc[NCLS];
        #pragma unroll
        for (int c = 0; c < NCLS; ++c) cc[c] = 0;
        #pragma unroll
        for (int j = 0; j < 4; ++j) {
            int4 v = l4[j];
            #pragma unroll
            for (int c = 0; c < NCLS; ++c)
                cc[c] += (v.x == c) + (v.y == c) + (v.z == c) + (v.w == c);
        }
        #pragma unroll
        for (int c = 0; c < NCLS; ++c) {
            int t = cc[c];
            #pragma unroll
            for (int dd = 1; dd < 64; dd <<= 1) t += __shfl_xor(t, dd, 64);
            if (lane == 0) whist[wv][c] = t;
        }
    }
    __syncthreads();
    if (tid == 0) {
        int o = 0, tb = 0;
        #pragma unroll
        for (int c = 0; c < NCLS; ++c) {
            int h = 0;
            #pragma unroll
            for (int w = 0; w < 8; ++w) h += whist[w][c];
            int T = (h + 127) >> 7;
            s_hist[c] = h; s_off[c] = o; s_tb[c] = tb;
            o += h; tb += T * (T + 1) / 2;
        }
        s_tb[NCLS] = tb;
    }
    __syncthreads();
    const int nT = s_tb[NCLS];

    for (int t = blockIdx.x; t < nT; t += gridDim.x) {
        int c = 0;
        while (t >= s_tb[c + 1]) ++c;
        int rem = t - s_tb[c];
        int T = (s_hist[c] + 127) >> 7;
        int ti = 0;
        while (rem >= T - ti) { rem -= (T - ti); ++ti; }   // ti<=tj
        const int tj  = ti + rem;
        const int bm  = s_off[c] + ti * 128;
        const int bn  = s_off[c] + tj * 128;
        const int end = s_off[c] + s_hist[c];
        const bool diag = (bm == bn);

        // stage K-step (64 cols at kb) into buffer p
        auto STAGE = [&](int p, int kb) {
            #pragma unroll
            for (int g = 0; g < 4; ++g) {
                int grp = wv + g * 8;             // 0..31, wave-uniform
                if (diag && grp >= 16) continue;  // diag: A tile only
                int idx = grp & 15;
                int kk2 = idx >> 3;
                int rg  = idx & 7;
                int row = (grp < 16 ? bm : bn) + rg * 16 + lc;
                row = min(row, end - 1);          // partial: dup last row, masked later
                int kcol = kb + kk2 * 32 + l8;
                const _Float16* src = X + (size_t)row * DIM + kcol;
                _Float16* dst = (grp < 16 ? &Atile[p][0] : &Btile[p][0])
                              + ((kk2 * 8 + rg) * 64 + lane) * 8;
                load16_g2l(dst, src);
            }
        };

        f32x4 acc[4][2] = {};

        STAGE(0, 0);
        __syncthreads();                          // stage-0 landed (vmcnt0+barrier)
        int cur = 0;
        for (int ks = 0; ks < 8; ++ks) {
            if (ks < 7) STAGE(cur ^ 1, (ks + 1) * 64);   // async prefetch
            const _Float16* Ab = &Atile[cur][0];
            const _Float16* Bb = diag ? Ab : &Btile[cur][0];
            #pragma unroll
            for (int kk2 = 0; kk2 < 2; ++kk2) {
                f16x8 af[4], bf[2];
                #pragma unroll
                for (int q = 0; q < 4; ++q)
                    af[q] = *(const f16x8*)&Ab[((kk2 * 8 + wr * 4 + q) * 64 + lane) * 8];
                #pragma unroll
                for (int q = 0; q < 2; ++q)
                    bf[q] = *(const f16x8*)&Bb[((kk2 * 8 + wc * 2 + q) * 64 + lane) * 8];
                #pragma unroll
                for (int mt = 0; mt < 4; ++mt)
                    #pragma unroll
                    for (int nt = 0; nt < 2; ++nt)
                        acc[mt][nt] = __builtin_amdgcn_mfma_f32_16x16x32_f16(
                            af[mt], bf[nt], acc[mt][nt], 0, 0, 0);
            }
            __syncthreads();                      // drains prefetch; LDS reuse safe
            cur ^= 1;
        }

        // epilogue. C/D: col = lane&15, row = (lane>>4)*4 + reg   [m89/m91]
        const int row0 = bm + wr * 64;
        const int col0 = bn + wc * 32;
        const float cs = 2.0f * 1.4426950408889634f;  // (1/T)*log2(e)

        float colsum[2] = {0.f, 0.f};
        #pragma unroll
        for (int mt = 0; mt < 4; ++mt) {
            #pragma unroll
            for (int r = 0; r < 4; ++r) {
                int grow = row0 + mt * 16 + lq * 4 + r;
                float s = 0.f;
                #pragma unroll
                for (int nt = 0; nt < 2; ++nt) {
                    int gcol = col0 + nt * 16 + lc;
                    float e = exp2f(acc[mt][nt][r] * cs);
                    bool ok = (gcol < end) && (!diag || (grow != gcol));
                    e = ok ? e : 0.f;
                    s += e;
                    colsum[nt] += e;
                }
                #pragma unroll
                for (int dd = 1; dd < 16; dd <<= 1) s += __shfl_xor(s, dd, 64);
                if (lc == 0 && grow < end) atomicAdd(&denom[grow], s);
            }
        }
        if (!diag) {  // mirrored tile's row-sums (row panels of off-diag are always full)
            #pragma unroll
            for (int nt = 0; nt < 2; ++nt) {
                float c2 = colsum[nt];
                c2 += __shfl_xor(c2, 16, 64);
                c2 += __shfl_xor(c2, 32, 64);
                int gcol = col0 + nt * 16 + lc;
                if (lq == 0 && gcol < end) atomicAdd(&denom[gcol], c2);
            }
        }
    }
}

// ---------------- 3. finalize: loss = mean(log denom) - sum(pos)/2048 ----------------
__global__ __launch_bounds__(256) void finalize_kernel(const float* __restrict__ denom,
                                                       const float* __restrict__ posPart,
                                                       float* __restrict__ loss) {
    const int tid = threadIdx.x;
    float v = 0.f;
    const float4* d4 = (const float4*)denom;
    #pragma unroll
    for (int i = 0; i < 8; ++i) {
        float4 q = d4[tid + i * 256];
        v += (__logf(q.x) + __logf(q.y) + __logf(q.z) + __logf(q.w)) * (1.0f / 8192.0f);
    }
    const float4* p4 = (const float4*)posPart;   // 512 floats = 128 float4
    if (tid < 128) {
        float4 q = p4[tid];
        v -= (q.x + q.y + q.z + q.w) * (1.0f / 2048.0f);
    }
    #pragma unroll
    for (int dd = 1; dd < 64; dd <<= 1) v += __shfl_xor(v, dd, 64);
    __shared__ float red[4];
    if ((tid & 63) == 0) red[tid >> 6] = v;
    __syncthreads();
    if (tid == 0) loss[0] = red[0] + red[1] + red[2] + red[3];
}

extern "C" void kernel_launch(void* const* d_in, const int* in_sizes, int n_in,
                              void* d_out, int out_size, void* d_ws, size_t ws_size,
                              hipStream_t stream) {
    const float* out_full = (const float*)d_in[0];  // [8192, 512]
    const int*   labels   = (const int*)d_in[3];    // [8192]
    float* loss = (float*)d_out;

    char* ws = (char*)d_ws;
    _Float16* Xs      = (_Float16*)ws;                 // 8 MiB
    float*    denomS  = (float*)(ws + 8388608);        // 32 KiB
    float*    posPart = (float*)(ws + 8421376);        // 2 KiB

    scatter_plan_kernel<<<512, 256, 0, stream>>>(out_full, labels, Xs, denomS, posPart);
    gemm_denom_kernel<<<GEMM_GRID, 512, 0, stream>>>(Xs, labels, denomS);
    finalize_kernel<<<1, 256, 0, stream>>>(denomS, posPart, loss);
}

// Round 17
// 111.590 us; speedup vs baseline: 1.0135x; 1.0135x over previous
//
#include <hip/hip_runtime.h>
#include <stdint.h>

// SimCLR clear loss, MI355X — round 21 (= round 16..20 resubmitted verbatim;
// five consecutive acquisition timeouts, kernel has never run. Audited 3x;
// deadlock-free by construction — no spin, last block finalizes).
//  - r15 coop launch FAILED SILENTLY (absmax == full loss => output zero;
//    launch rejected). Cooperative path abandoned.
//  - Verified r9 structure; finalize folded into gemm via completion counter.
//    Release = vmcnt(0)+barrier (denom ops are device-scope atomics, coherent
//    at LLC — no cache writeback needed). Acquire = ONE __threadfence in the
//    last block only (r5's disaster was 6144 per-wave fences; this is 1).
//  - counter zeroed by scatter block 0 (kernel-boundary visibility;
//    re-zeroed every launch => graph-replay idempotent).
//  - Fallback if this fails on HW: r9 3-kernel chain (110.9 us verified).

#define NROWS 8192
#define DIM   512
#define NCLS  7
#define GEMM_GRID 512

typedef _Float16 f16x8 __attribute__((ext_vector_type(8)));
typedef float    f32x4 __attribute__((ext_vector_type(4)));

__device__ __forceinline__ void load16_g2l(void* lds, const void* g) {
    auto* l3 = reinterpret_cast<__attribute__((address_space(3))) uint32_t*>(
        reinterpret_cast<uintptr_t>(lds));
    auto* g1 = reinterpret_cast<const __attribute__((address_space(1))) uint32_t*>(
        reinterpret_cast<uintptr_t>(g));
    __builtin_amdgcn_global_load_lds(g1, l3, 16, 0, 0);
}

// ---------------- 1. fused plan + scatter + cast + pos dot ----------------
// Block b (of 512): first-view rows 8b..8b+7 (waves 0,1: 4 each),
// second-view rows +4096 (waves 2,3). All rows of a wave share one segment.
// Per-block redundant plan: 8192 labels -> cnt[128][7] in LDS -> packed
// (prefix|full<<16) shuffle reduction gives this wave's wavebase[7].
__global__ __launch_bounds__(256) void scatter_plan_kernel(const float* __restrict__ x,
                                                           const int* __restrict__ labels,
                                                           _Float16* __restrict__ y,
                                                           float* __restrict__ denomS,
                                                           float* __restrict__ posPart,
                                                           int* __restrict__ counter) {
    __shared__ int    halfc[256][8];     // per-half-segment class counts
    __shared__ int    cnt[128][8];       // per-segment class counts
    __shared__ float4 xch[8][128];       // second-view rows for pos dot
    __shared__ float  red[2];
    const int tid  = threadIdx.x;
    const int lane = tid & 63;
    const int wv   = tid >> 6;
    const int b    = blockIdx.x;

    {   // count 32 labels (= half of segment tid>>1)
        const int4* l4 = (const int4*)labels + tid * 8;
        int c0 = 0, c1 = 0, c2 = 0, c3 = 0, c4 = 0, c5 = 0, c6 = 0;
        #pragma unroll
        for (int j = 0; j < 8; ++j) {
            int4 v = l4[j];
            c0 += (v.x == 0) + (v.y == 0) + (v.z == 0) + (v.w == 0);
            c1 += (v.x == 1) + (v.y == 1) + (v.z == 1) + (v.w == 1);
            c2 += (v.x == 2) + (v.y == 2) + (v.z == 2) + (v.w == 2);
            c3 += (v.x == 3) + (v.y == 3) + (v.z == 3) + (v.w == 3);
            c4 += (v.x == 4) + (v.y == 4) + (v.z == 4) + (v.w == 4);
            c5 += (v.x == 5) + (v.y == 5) + (v.z == 5) + (v.w == 5);
            c6 += (v.x == 6) + (v.y == 6) + (v.z == 6) + (v.w == 6);
        }
        halfc[tid][0] = c0; halfc[tid][1] = c1; halfc[tid][2] = c2;
        halfc[tid][3] = c3; halfc[tid][4] = c4; halfc[tid][5] = c5;
        halfc[tid][6] = c6;
    }
    __syncthreads();
    if (tid < 128) {
        #pragma unroll
        for (int c = 0; c < NCLS; ++c)
            cnt[tid][c] = halfc[2 * tid][c] + halfc[2 * tid + 1][c];
    }
    __syncthreads();

    // wave's segment: waves 0,1 -> b>>3 ; waves 2,3 -> b>>3 + 64
    const int s = (b >> 3) + (wv >> 1) * 64;

    // wavebase[c] = class_offset(c) + sum_{s'<s} cnt[s'][c], via packed reduce
    int wb[NCLS];
    {
        int o = 0;
        #pragma unroll
        for (int c = 0; c < NCLS; ++c) {
            int a0 = cnt[lane][c], a1 = cnt[lane + 64][c];
            int p = (lane < s ? a0 : 0) + (lane + 64 < s ? a1 : 0);
            int packed = p | ((a0 + a1) << 16);
            #pragma unroll
            for (int dd = 1; dd < 64; dd <<= 1) packed += __shfl_xor(packed, dd, 64);
            wb[c] = o + (packed & 0xffff);
            o += (packed >> 16);
        }
    }

    // ballot rank within segment
    const int lab = labels[s * 64 + lane];
    unsigned long long m0 = __ballot(lab == 0), m1 = __ballot(lab == 1),
                       m2 = __ballot(lab == 2), m3 = __ballot(lab == 3),
                       m4 = __ballot(lab == 4), m5 = __ballot(lab == 5),
                       m6 = __ballot(lab == 6);
    unsigned long long mymask =
        lab == 0 ? m0 : lab == 1 ? m1 : lab == 2 ? m2 : lab == 3 ? m3 :
        lab == 4 ? m4 : lab == 5 ? m5 : m6;
    int wbsel = lab == 0 ? wb[0] : lab == 1 ? wb[1] : lab == 2 ? wb[2] :
                lab == 3 ? wb[3] : lab == 4 ? wb[4] : lab == 5 ? wb[5] : wb[6];
    const unsigned long long lt = (1ull << lane) - 1ull;
    const int dest_lane = wbsel + __builtin_popcountll(mymask & lt);

    // load 4 rows (lane covers contiguous 8 floats: float4 pair 2*lane, 2*lane+1)
    const int r0 = b * 8 + (wv & 1) * 4 + (wv >> 1) * 4096;
    float4 va[8];
    #pragma unroll
    for (int j = 0; j < 4; ++j) {
        const float4* src = (const float4*)(x + (size_t)(r0 + j) * DIM);
        va[2 * j]     = src[2 * lane];
        va[2 * j + 1] = src[2 * lane + 1];
    }
    if (wv >= 2) {      // publish second view for the pos dot
        #pragma unroll
        for (int j = 0; j < 4; ++j) {
            xch[(wv - 2) * 4 + j][2 * lane]     = va[2 * j];
            xch[(wv - 2) * 4 + j][2 * lane + 1] = va[2 * j + 1];
        }
    }

    // cast + scatter store: one 16B f16x8 per row per lane
    #pragma unroll
    for (int j = 0; j < 4; ++j) {
        int dest = __shfl(dest_lane, (r0 + j) & 63, 64);
        f16x8 h;
        h[0] = (_Float16)va[2 * j].x;     h[1] = (_Float16)va[2 * j].y;
        h[2] = (_Float16)va[2 * j].z;     h[3] = (_Float16)va[2 * j].w;
        h[4] = (_Float16)va[2 * j + 1].x; h[5] = (_Float16)va[2 * j + 1].y;
        h[6] = (_Float16)va[2 * j + 1].z; h[7] = (_Float16)va[2 * j + 1].w;
        *(f16x8*)(y + (size_t)dest * DIM + lane * 8) = h;
    }

    __syncthreads();
    if (wv < 2) {       // first view: dot against paired second-view rows
        float acc = 0.f;
        #pragma unroll
        for (int j = 0; j < 4; ++j) {
            float4 b0 = xch[wv * 4 + j][2 * lane];
            float4 b1 = xch[wv * 4 + j][2 * lane + 1];
            acc += va[2 * j].x * b0.x + va[2 * j].y * b0.y
                 + va[2 * j].z * b0.z + va[2 * j].w * b0.w
                 + va[2 * j + 1].x * b1.x + va[2 * j + 1].y * b1.y
                 + va[2 * j + 1].z * b1.z + va[2 * j + 1].w * b1.w;
        }
        #pragma unroll
        for (int dd = 1; dd < 64; dd <<= 1) acc += __shfl_xor(acc, dd, 64);
        if (lane == 0) red[wv] = acc;
    }
    __syncthreads();
    if (tid == 0) posPart[b] = red[0] + red[1];
    if (tid < 4) ((float4*)denomS)[b * 4 + tid] = make_float4(0.f, 0.f, 0.f, 0.f);
    if (b == 0 && tid == 0) counter[0] = 0;
}

// ---------------- 2. GEMM over triangular class tiles + last-block finalize ----------------
// Tile list derived from per-block 7-bin label histogram. 8 waves, each a
// 64x32 quadrant; LDS fragment-ordered [2][8][64][8]; off-diag tiles emit
// row+col sums (S^T reuse); diag masks i!=j. Completion counter: last block
// (single __threadfence acquire) computes loss = mean(log denom) - sum(pos)/2048.
__global__ __launch_bounds__(512) void gemm_denom_kernel(const _Float16* __restrict__ X,
                                                         const int* __restrict__ labels,
                                                         float* __restrict__ denom,
                                                         const float* __restrict__ posPart,
                                                         int* __restrict__ counter,
                                                         float* __restrict__ loss) {
    __shared__ __align__(16) _Float16 Atile[8192];  // [2][8][64][8] = 16 KiB
    __shared__ __align__(16) _Float16 Btile[8192];
    __shared__ int whist[8][8];
    __shared__ int s_hist[8], s_off[8], s_tb[8];
    __shared__ int lastFlag;

    const int tid  = threadIdx.x;
    const int lane = tid & 63;
    const int wv   = tid >> 6;       // 0..7
    const int lc   = lane & 15;
    const int lq   = lane >> 4;
    const int l8   = lq * 8;
    const int wr   = wv >> 2;        // 0..1 : 64-row half
    const int wc   = wv & 3;         // 0..3 : 32-col quarter

    {   // class histogram: 512 threads x 16 labels, wave shuffle reduce
        const int4* l4 = (const int4*)labels + tid * 4;
        int cc[NCLS];
        #pragma unroll
        for (int c = 0; c < NCLS; ++c) cc[c] = 0;
        #pragma unroll
        for (int j = 0; j < 4; ++j) {
            int4 v = l4[j];
            #pragma unroll
            for (int c = 0; c < NCLS; ++c)
                cc[c] += (v.x == c) + (v.y == c) + (v.z == c) + (v.w == c);
        }
        #pragma unroll
        for (int c = 0; c < NCLS; ++c) {
            int t = cc[c];
            #pragma unroll
            for (int dd = 1; dd < 64; dd <<= 1) t += __shfl_xor(t, dd, 64);
            if (lane == 0) whist[wv][c] = t;
        }
    }
    __syncthreads();
    if (tid == 0) {
        int o = 0, tb = 0;
        #pragma unroll
        for (int c = 0; c < NCLS; ++c) {
            int h = 0;
            #pragma unroll
            for (int w = 0; w < 8; ++w) h += whist[w][c];
            int T = (h + 127) >> 7;
            s_hist[c] = h; s_off[c] = o; s_tb[c] = tb;
            o += h; tb += T * (T + 1) / 2;
        }
        s_tb[NCLS] = tb;
    }
    __syncthreads();
    const int nT = s_tb[NCLS];

    for (int t = blockIdx.x; t < nT; t += gridDim.x) {
        int c = 0;
        while (t >= s_tb[c + 1]) ++c;
        int rem = t - s_tb[c];
        int T = (s_hist[c] + 127) >> 7;
        int ti = 0;
        while (rem >= T - ti) { rem -= (T - ti); ++ti; }   // ti<=tj
        const int tj  = ti + rem;
        const int bm  = s_off[c] + ti * 128;
        const int bn  = s_off[c] + tj * 128;
        const int end = s_off[c] + s_hist[c];
        const bool diag = (bm == bn);

        f32x4 acc[4][2] = {};

        for (int kb = 0; kb < DIM; kb += 64) {
            __syncthreads();
            #pragma unroll
            for (int g = 0; g < 4; ++g) {
                int grp = wv + g * 8;             // 0..31, wave-uniform
                if (diag && grp >= 16) continue;  // diag: A tile only
                int idx = grp & 15;
                int kk2 = idx >> 3;
                int rg  = idx & 7;
                int row = (grp < 16 ? bm : bn) + rg * 16 + lc;
                row = min(row, end - 1);          // partial: dup last row, masked later
                int kcol = kb + kk2 * 32 + l8;
                const _Float16* src = X + (size_t)row * DIM + kcol;
                _Float16* dst = (grp < 16 ? Atile : Btile) + ((kk2 * 8 + rg) * 64 + lane) * 8;
                load16_g2l(dst, src);
            }
            __syncthreads();

            const _Float16* Bbase = diag ? Atile : Btile;
            #pragma unroll
            for (int kk2 = 0; kk2 < 2; ++kk2) {
                f16x8 af[4], bf[2];
                #pragma unroll
                for (int q = 0; q < 4; ++q)
                    af[q] = *(const f16x8*)&Atile[((kk2 * 8 + wr * 4 + q) * 64 + lane) * 8];
                #pragma unroll
                for (int q = 0; q < 2; ++q)
                    bf[q] = *(const f16x8*)&Bbase[((kk2 * 8 + wc * 2 + q) * 64 + lane) * 8];
                #pragma unroll
                for (int mt = 0; mt < 4; ++mt)
                    #pragma unroll
                    for (int nt = 0; nt < 2; ++nt)
                        acc[mt][nt] = __builtin_amdgcn_mfma_f32_16x16x32_f16(
                            af[mt], bf[nt], acc[mt][nt], 0, 0, 0);
            }
        }

        // epilogue. C/D: col = lane&15, row = (lane>>4)*4 + reg   [m89/m91]
        const int row0 = bm + wr * 64;
        const int col0 = bn + wc * 32;
        const float cs = 2.0f * 1.4426950408889634f;  // (1/T)*log2(e)

        float colsum[2] = {0.f, 0.f};
        #pragma unroll
        for (int mt = 0; mt < 4; ++mt) {
            #pragma unroll
            for (int r = 0; r < 4; ++r) {
                int grow = row0 + mt * 16 + lq * 4 + r;
                float s = 0.f;
                #pragma unroll
                for (int nt = 0; nt < 2; ++nt) {
                    int gcol = col0 + nt * 16 + lc;
                    float e = exp2f(acc[mt][nt][r] * cs);
                    bool ok = (gcol < end) && (!diag || (grow != gcol));
                    e = ok ? e : 0.f;
                    s += e;
                    colsum[nt] += e;
                }
                #pragma unroll
                for (int dd = 1; dd < 16; dd <<= 1) s += __shfl_xor(s, dd, 64);
                if (lc == 0 && grow < end) atomicAdd(&denom[grow], s);
            }
        }
        if (!diag) {  // mirrored tile's row-sums (row panels of off-diag are always full)
            #pragma unroll
            for (int nt = 0; nt < 2; ++nt) {
                float c2 = colsum[nt];
                c2 += __shfl_xor(c2, 16, 64);
                c2 += __shfl_xor(c2, 32, 64);
                int gcol = col0 + nt * 16 + lc;
                if (lq == 0 && gcol < end) atomicAdd(&denom[gcol], c2);
            }
        }
    }

    // ---- completion: last block finalizes. Release = vmcnt(0)+barrier
    // (denom writes are device-scope atomics, performed at LLC when retired);
    // acquire = ONE __threadfence in the last block only. ----
    asm volatile("s_waitcnt vmcnt(0)" ::: "memory");
    __syncthreads();
    if (tid == 0) lastFlag = (atomicAdd(counter, 1) == (int)gridDim.x - 1);
    __syncthreads();
    if (lastFlag) {
        __threadfence();               // invalidate stale cached denom lines
        float v = 0.f;
        const float4* d4 = (const float4*)denom;
        #pragma unroll
        for (int i = 0; i < 4; ++i) {
            float4 q = d4[tid + i * 512];
            v += (__logf(q.x) + __logf(q.y) + __logf(q.z) + __logf(q.w)) * (1.0f / 8192.0f);
        }
        if (tid < 128) {
            float4 q = ((const float4*)posPart)[tid];
            v -= (q.x + q.y + q.z + q.w) * (1.0f / 2048.0f);
        }
        #pragma unroll
        for (int dd = 1; dd < 64; dd <<= 1) v += __shfl_xor(v, dd, 64);
        __shared__ float redf[8];
        if (lane == 0) redf[wv] = v;
        __syncthreads();
        if (tid == 0)
            loss[0] = redf[0] + redf[1] + redf[2] + redf[3]
                    + redf[4] + redf[5] + redf[6] + redf[7];
    }
}

extern "C" void kernel_launch(void* const* d_in, const int* in_sizes, int n_in,
                              void* d_out, int out_size, void* d_ws, size_t ws_size,
                              hipStream_t stream) {
    const float* out_full = (const float*)d_in[0];  // [8192, 512]
    const int*   labels   = (const int*)d_in[3];    // [8192]
    float* loss = (float*)d_out;

    char* ws = (char*)d_ws;
    _Float16* Xs      = (_Float16*)ws;                 // 8 MiB
    float*    denomS  = (float*)(ws + 8388608);        // 32 KiB
    float*    posPart = (float*)(ws + 8421376);        // 2 KiB
    int*      counter = (int*)(ws + 8423424);          // 4 B

    scatter_plan_kernel<<<512, 256, 0, stream>>>(out_full, labels, Xs, denomS,
                                                 posPart, counter);
    gemm_denom_kernel<<<GEMM_GRID, 512, 0, stream>>>(Xs, labels, denomS,
                                                     posPart, counter, loss);
}